// Round 5
// baseline (119.373 us; speedup 1.0000x reference)
//
#include <hip/hip_runtime.h>
#include <stdint.h>

typedef _Float16 half8 __attribute__((ext_vector_type(8)));
typedef float f32x16 __attribute__((ext_vector_type(16)));

// ---------------- layout ----------------
// th : theta^T fp16, [i(3)][f(64)][k(1728)], k = j*576 + c*18 + m
//      m<17: w_spline*cp[m] ; m==17: w_silu
// A (built in-kernel, LDS): per output px row, k-chunk = 144 = (one j, 8 c's):
//      local k = (c-c0)*18 + m. Hat basis is a partition of unity: only
//      h[f0]=1-frac, h[f0+1]=frac (f0=min(floor(u),15)) and silu (m=17) are
//      nonzero => zero-init tile once, scatter 3 halves/(px,c)/chunk,
//      clear the 2 stale hat slots from the previous chunk.
#define NTH  (3 * 64 * 1728)             // 331776
#define PREP_BLOCKS (NTH / 256)          // 1296 exactly

__global__ __launch_bounds__(256) void kan_prep(
    const float* __restrict__ cp, const float* __restrict__ wspl,
    const float* __restrict__ wsil, _Float16* __restrict__ th)
{
    int e  = blockIdx.x * 256 + threadIdx.x;   // < NTH exactly
    int k  = e % 1728;
    int fi = e / 1728;
    int f  = fi & 63;
    int i  = fi >> 6;
    int j  = k / 576;
    int q  = k - j * 576;
    int c  = q / 18;
    int m  = q - c * 18;
    int base = ((f * 32 + c) * 3 + i) * 3 + j;           // (F,C,3,3) flat
    float v = (m < 17) ? wspl[base] * cp[base * 17 + m] : wsil[base];
    th[e] = (_Float16)v;
}

// Fused GEMM: block = 256 thr = 4 waves (2 px-halves x 2 f-halves),
// tile 64 px x 64 f, i = blockIdx.y. K = 1728 in 12 chunks of 144
// (j = ch>>2, c-octet = ch&3). A-tile computed from x (L2-resident);
// B staged from th (L2-resident). LDS rows 152 halves (304 B = 19*16:
// all b128 frag reads 16B-aligned, 2-way-max bank aliasing = free).
// Single-buffer A+B, 2 barriers/chunk, reg-prefetch B (5x uint4) + x
// (float2) issued one chunk ahead. 38.9 KB LDS -> 4 blocks/CU.
__global__ __launch_bounds__(256) void kan_main(
    const float* __restrict__ x, const _Float16* __restrict__ th,
    const float* __restrict__ bias, float* __restrict__ out)
{
    __shared__ __align__(16) _Float16 lA[64 * 152];    // 19456 B
    __shared__ __align__(16) _Float16 lB[64 * 152];    // 19456 B

    const int bx = blockIdx.x;                     // b = bx>>6, ho = bx&63
    const int i  = blockIdx.y;                     // 0..2
    const int b  = bx >> 6;
    const int ho = bx & 63;

    const int tid  = threadIdx.x;                  // 0..255
    const int wv   = tid >> 6;
    const int wpx  = wv >> 1;                      // px half
    const int wf   = wv & 1;                       // f half
    const int lane = tid & 63;
    const int r31  = lane & 31;
    const int kh   = lane >> 5;

    // ---- B staging map: 64 rows x 288 B = 1152 16B-units; unit id = tid+256r
    int goffB[5], doffB[5];
#pragma unroll
    for (int r = 0; r < 5; ++r) {
        int id  = tid + 256 * r;
        int row = id / 18;
        int u   = id - row * 18;
        goffB[r] = row * 3456 + u * 16;            // + j*1152 + oct*288
        doffB[r] = row * 304 + u * 16;
    }
    const char* thb = (const char*)(th + (size_t)(i * 64) * 1728);

    // ---- A feature map: thread owns (px = tid>>2, c-pair cc = tid&3)
    const int apx = tid >> 2;
    const int cc  = tid & 3;
    const float* xrow = x + ((size_t)((b * 66 + ho + i) * 66 + apx)) * 32;
    char* aBase = (char*)lA + apx * 304 + cc * 72; // 36-half region [d0|d1]
    // stale-slot pointers, init to harmless in-region slots (m=15; all zero)
    char* pprev0 = aBase + 30;
    char* pprev1 = aBase + 36 + 30;

    // ---- zero lA once (2432 b64 units / 256 thr)
    for (int o = tid * 8; o < 64 * 304; o += 2048)
        *(uint64_t*)((char*)lA + o) = 0ull;

    // ---- prefetch chunk 0
    uint4 bPF[5];
    float2 xPF;
    {
#pragma unroll
        for (int r = 0; r < 5; ++r)
            if (r < 4 || tid < 128)
                bPF[r] = *(const uint4*)(thb + goffB[r]);
        xPF = *(const float2*)(xrow + cc * 2);
    }

    f32x16 acc;
    {
        float bv = (i == 1) ? bias[wf * 32 + r31] : 0.0f;
#pragma unroll
        for (int r = 0; r < 16; ++r) acc[r] = bv;
    }

    const _Float16* pa = lA + (wpx * 32 + r31) * 152 + kh * 8;
    const _Float16* pb = lB + (wf  * 32 + r31) * 152 + kh * 8;

    __syncthreads();                               // zero-init visible

#pragma unroll
    for (int ch = 0; ch < 12; ++ch) {
        const int jn = ch >> 2, octn = ch & 3;
        // ---- stage B (consume prefetch regs)
#pragma unroll
        for (int r = 0; r < 5; ++r)
            if (r < 4 || tid < 128)
                *(uint4*)((char*)lB + doffB[r]) = bPF[r];
        // ---- re-issue B prefetch for next chunk
        if (ch < 11) {
            const int j2 = (ch + 1) >> 2, o2 = (ch + 1) & 3;
            const int kb2 = j2 * 1152 + o2 * 288;
#pragma unroll
            for (int r = 0; r < 5; ++r)
                if (r < 4 || tid < 128)
                    bPF[r] = *(const uint4*)(thb + goffB[r] + kb2);
        }
        // ---- build A: clear stale hat slots, scatter 3 halves per (px,c)
        {
            float p0 = xPF.x, p1 = xPF.y;
            *(_Float16*)(pprev0) = (_Float16)0.0f;
            *(_Float16*)(pprev0 + 2) = (_Float16)0.0f;
            *(_Float16*)(pprev1) = (_Float16)0.0f;
            *(_Float16*)(pprev1 + 2) = (_Float16)0.0f;
            // d = 0
            {
                float xc = fminf(1.0f, fmaxf(-1.0f, p0));
                float u  = fmaf(xc, 8.0f, 8.0f);
                int  f0  = min((int)u, 15);
                float fr = u - (float)f0;
                char* ad = aBase + f0 * 2;
                *(_Float16*)(ad)     = (_Float16)(1.0f - fr);
                *(_Float16*)(ad + 2) = (_Float16)fr;
                *(_Float16*)(aBase + 34) =
                    (_Float16)(p0 * __builtin_amdgcn_rcpf(1.0f + __expf(-p0)));
                pprev0 = ad;
            }
            // d = 1
            {
                float xc = fminf(1.0f, fmaxf(-1.0f, p1));
                float u  = fmaf(xc, 8.0f, 8.0f);
                int  f0  = min((int)u, 15);
                float fr = u - (float)f0;
                char* ad = aBase + 36 + f0 * 2;
                *(_Float16*)(ad)     = (_Float16)(1.0f - fr);
                *(_Float16*)(ad + 2) = (_Float16)fr;
                *(_Float16*)(aBase + 36 + 34) =
                    (_Float16)(p1 * __builtin_amdgcn_rcpf(1.0f + __expf(-p1)));
                pprev1 = ad;
            }
        }
        // ---- re-issue x prefetch for next chunk
        if (ch < 11) {
            const int j2 = (ch + 1) >> 2, o2 = (ch + 1) & 3;
            xPF = *(const float2*)(xrow + j2 * 32 + o2 * 8 + cc * 2);
        }
        __syncthreads();                           // A, B ready
        // ---- 9 MFMA k-steps over the 144-k chunk
#pragma unroll
        for (int s = 0; s < 9; ++s) {
            half8 a  = *(const half8*)(pa + s * 16);
            half8 bf = *(const half8*)(pb + s * 16);
            acc = __builtin_amdgcn_mfma_f32_32x32x16_f16(a, bf, acc, 0, 0, 0);
        }
        if (ch < 11) __syncthreads();              // readers done
    }

    // C/D layout (verified): col = lane&31, row = (reg&3)+8*(reg>>2)+4*(lane>>5)
    float* obase = out
        + ((size_t)((b * 64 + ho) * 64 + wpx * 32)) * 64 + wf * 32;
#pragma unroll
    for (int r = 0; r < 16; ++r) {
        int rowD = (r & 3) + 8 * (r >> 2) + 4 * kh;  // px within the 32-block
        atomicAdd(obase + (size_t)rowD * 64 + r31, acc[r]);
    }
}

extern "C" void kernel_launch(void* const* d_in, const int* in_sizes, int n_in,
                              void* d_out, int out_size, void* d_ws, size_t ws_size,
                              hipStream_t stream) {
    const float* x    = (const float*)d_in[0];
    const float* cp   = (const float*)d_in[1];
    const float* wspl = (const float*)d_in[2];
    const float* wsil = (const float*)d_in[3];
    const float* bias = (const float*)d_in[4];
    float* out = (float*)d_out;

    _Float16* th = (_Float16*)d_ws;

    kan_prep<<<PREP_BLOCKS, 256, 0, stream>>>(cp, wspl, wsil, th);
    hipMemsetAsync(d_out, 0, (size_t)out_size * 4, stream);

    dim3 grid(256, 3);
    kan_main<<<grid, 256, 0, stream>>>(x, th, bias, out);
}